// Round 17
// baseline (617.942 us; speedup 1.0000x reference)
//
#include <hip/hip_runtime.h>

#define NN 50000
#define NE 800000
#define NG 512
#define TPB 256
#define BN_EPS 1e-5f
#define NBLK_G 400       // GEMM grid: ceil(NN/128)=391, padded to 400
#define EDGE_BLKS 3125   // NE/TPB exactly
#define EMB_BLKS 6250    // NN*32/TPB exactly
#define HIST_BLKS 256
#define HIST_EPB 3125    // NE/HIST_BLKS
#define HIST_WORDS 12500 // NN/4 packed u8x4 words

typedef __attribute__((ext_vector_type(8))) short bf16x8;
typedef __attribute__((ext_vector_type(4))) float f32x4;

__device__ __forceinline__ float bf2f(unsigned u) {  // low 16 bits = bf16
  return __uint_as_float(u << 16);
}
__device__ __forceinline__ unsigned f2bf(float f) {
  unsigned u = __float_as_uint(f);
  u += 0x7FFFu + ((u >> 16) & 1u);  // round-to-nearest-even
  return u >> 16;
}

// Convert all layers' W1/W2 to bf16 once; zero the tail-block counter
// (d_ws is poisoned to 0xAA, so the counter must be zeroed every launch).
__global__ void k_wcvt(const float* __restrict__ W1, const float* __restrict__ W2,
                       unsigned short* __restrict__ w1b, unsigned short* __restrict__ w2b,
                       int* __restrict__ ctr) {
  int i = blockIdx.x * TPB + threadIdx.x;  // 65536 threads
  if (i == 0) *ctr = 0;
  if (i < 32768)
    w1b[i] = (unsigned short)f2bf(W1[i]);
  else
    w2b[i - 32768] = (unsigned short)f2bf(W2[i - 32768]);
}

// Pass 1: per-block LDS-privatized histogram + per-edge within-block rank.
__global__ __launch_bounds__(TPB) void k_hist_lds(const int* __restrict__ dst,
                                                  unsigned* __restrict__ partial,
                                                  unsigned char* __restrict__ rank8) {
  __shared__ unsigned hist[HIST_WORDS];
  const int t = threadIdx.x, b = blockIdx.x;
  for (int w = t; w < HIST_WORDS; w += TPB) hist[w] = 0u;
  __syncthreads();
  const int* dp = dst + b * HIST_EPB;
  unsigned char* rp = rank8 + b * HIST_EPB;
  for (int it = t; it < HIST_EPB; it += TPB) {
    int d = dp[it];
    unsigned sh = 8u * (d & 3);
    unsigned old = atomicAdd(&hist[d >> 2], 1u << sh);
    rp[it] = (unsigned char)((old >> sh) & 255u);
  }
  __syncthreads();
  unsigned* out = partial + (size_t)b * HIST_WORDS;
  for (int w = t; w < HIST_WORDS; w += TPB) out[w] = hist[w];
}

// Pass 2: exclusive prefix over HIST_BLKS block histograms in place; counts.
__global__ void k_hist_scan(unsigned* __restrict__ partial, int* __restrict__ counts) {
  int w = blockIdx.x * TPB + threadIdx.x;
  if (w >= HIST_WORDS) return;
  unsigned run = 0;
#pragma unroll 8
  for (int b = 0; b < HIST_BLKS; ++b) {
    unsigned v = partial[(size_t)b * HIST_WORDS + w];
    partial[(size_t)b * HIST_WORDS + w] = run;
    run += v;
  }
  *(int4*)&counts[4 * w] = make_int4((int)(run & 255u), (int)((run >> 8) & 255u),
                                     (int)((run >> 16) & 255u), (int)(run >> 24));
}

__global__ void k_scan1(const int* __restrict__ counts, int* __restrict__ incl,
                        int* __restrict__ btot) {
  __shared__ int lds[TPB];
  int i = blockIdx.x * TPB + threadIdx.x;
  int v = (i < NN) ? counts[i] : 0;
  lds[threadIdx.x] = v;
  __syncthreads();
  for (int off = 1; off < TPB; off <<= 1) {
    int t = (threadIdx.x >= off) ? lds[threadIdx.x - off] : 0;
    __syncthreads();
    lds[threadIdx.x] += t;
    __syncthreads();
  }
  if (i < NN) incl[i] = lds[threadIdx.x];
  if (threadIdx.x == TPB - 1) btot[blockIdx.x] = lds[TPB - 1];
}

__global__ void k_scan23(const int* __restrict__ incl, const int* __restrict__ btot,
                         int* __restrict__ row_ptr) {
  __shared__ int lds[TPB];
  const int t = threadIdx.x, b = blockIdx.x;
  lds[t] = (t < 196 && t < b) ? btot[t] : 0;
  __syncthreads();
  for (int off = TPB / 2; off > 0; off >>= 1) {
    if (t < off) lds[t] += lds[t + off];
    __syncthreads();
  }
  int S = lds[0];
  int i = b * TPB + t;
  if (i == 0) row_ptr[0] = 0;
  if (i < NN) row_ptr[i + 1] = incl[i] + S;
}

// LDS-free atomic-free fill + embed at full occupancy.
__global__ __launch_bounds__(TPB) void k_fill_embed(
    const int* __restrict__ src, const int* __restrict__ dst,
    const unsigned* __restrict__ partial, const unsigned char* __restrict__ rank8,
    const int* __restrict__ row_ptr, unsigned short* __restrict__ srcs,
    const int* __restrict__ x, const float* __restrict__ emb,
    unsigned* __restrict__ h_bf) {
  int b = blockIdx.x;
  if (b < EDGE_BLKS) {
    int e = b * TPB + threadIdx.x;
    int d = dst[e];
    int bh = e / HIST_EPB;
    unsigned base = (partial[(size_t)bh * HIST_WORDS + (d >> 2)] >> (8u * (d & 3))) & 255u;
    int pos = row_ptr[d] + (int)base + (int)rank8[e];
    srcs[pos] = (unsigned short)src[e];
  } else {
    int i = (b - EDGE_BLKS) * TPB + threadIdx.x;  // < NN*32 exactly
    int n = i >> 5, l = i & 31;
    float2 ev = *(const float2*)&emb[x[n] * 64 + 2 * l];
    h_bf[i] = f2bf(ev.x) | (f2bf(ev.y) << 16);
  }
}

// Aggregate over bf16 h, optional BN affine folded in -> packed bf16.
// Clamped batch-16 (r15): always 8 gathers in flight per half-wave.
template <bool BN>
__global__ void k_aggregate_bf(const unsigned* __restrict__ h_bf,
                               const int* __restrict__ row_ptr,
                               const unsigned short* __restrict__ srcs,
                               const float* __restrict__ bnst,
                               unsigned* __restrict__ zb) {
  int wid = (blockIdx.x * TPB + threadIdx.x) >> 6;
  int lane = threadIdx.x & 63;
  if (wid >= NN) return;
  int half = lane >> 5, l = lane & 31;
  int beg = row_ptr[wid], end = row_ptr[wid + 1];
  float a0 = 0.f, a1 = 0.f;
  if (half == 0) {
    unsigned u = h_bf[(size_t)wid * 32 + l];
    a0 = bf2f(u & 0xFFFF);
    a1 = bf2f(u >> 16);
  }
  for (int e = beg + half; e < end; e += 16) {
    int idx[8];
#pragma unroll
    for (int k = 0; k < 8; ++k) {
      int ee = e + 2 * k;
      idx[k] = srcs[ee < end ? ee : end - 1];
    }
    unsigned uu[8];
#pragma unroll
    for (int k = 0; k < 8; ++k) uu[k] = h_bf[(size_t)idx[k] * 32 + l];
#pragma unroll
    for (int k = 0; k < 8; ++k) {
      bool v = (e + 2 * k) < end;
      a0 += v ? bf2f(uu[k] & 0xFFFF) : 0.f;
      a1 += v ? bf2f(uu[k] >> 16) : 0.f;
    }
  }
  a0 += __shfl_xor(a0, 32);
  a1 += __shfl_xor(a1, 32);
  if (half == 0) {
    float zv0, zv1;
    if constexpr (BN) {
      float2 scv = *(const float2*)&bnst[2 * l];
      float2 shv = *(const float2*)&bnst[64 + 2 * l];
      float d1 = (float)(1 + end - beg);
      zv0 = fmaf(scv.x, a0, d1 * shv.x);
      zv1 = fmaf(scv.y, a1, d1 * shv.y);
    } else {
      zv0 = a0;
      zv1 = a1;
    }
    zb[(size_t)wid * 32 + l] = f2bf(zv0) | (f2bf(zv1) << 16);
  }
}

// MFMA GEMM1 with fused tail-block BN finalize: z2 = z @ W1 + b1 (bf16),
// per-block column stats -> partials; the LAST block (device counter) folds
// all partials and emits fused affine [scale128|shift128] into stout.
__global__ __launch_bounds__(TPB) void k_gemm1(const unsigned short* __restrict__ zb,
                                               const unsigned short* __restrict__ w1b,
                                               const float* __restrict__ bias,
                                               unsigned short* __restrict__ z2b,
                                               float* __restrict__ partials,
                                               const float* __restrict__ gamma,
                                               const float* __restrict__ beta,
                                               float* __restrict__ stout,
                                               int* __restrict__ ctr) {
  __shared__ __align__(16) unsigned short WTl[128 * 72];  // 18KB; reused for stats
  __shared__ int lastf;
  const int t = threadIdx.x;
  const int r0 = blockIdx.x * 128;
#pragma unroll
  for (int it = 0; it < 4096 / TPB; ++it) {
    int i2 = t + it * TPB;
    unsigned v = ((const unsigned*)w1b)[i2];
    int idx = 2 * i2;
    int k = idx >> 7, n = idx & 127;  // n even
    WTl[n * 72 + k] = (unsigned short)(v & 0xFFFF);
    WTl[(n + 1) * 72 + k] = (unsigned short)(v >> 16);
  }
  __syncthreads();

  const int w = t >> 6, lane = t & 63;
  const int m16 = lane & 15, kg = lane >> 4;
  bf16x8 a0[2], a1[2];
#pragma unroll
  for (int mi = 0; mi < 2; ++mi) {
    int ra = r0 + w * 32 + mi * 16 + m16;
    a0[mi] = bf16x8{0, 0, 0, 0, 0, 0, 0, 0};
    a1[mi] = bf16x8{0, 0, 0, 0, 0, 0, 0, 0};
    if (ra < NN) {
      a0[mi] = *(const bf16x8*)&zb[(size_t)ra * 64 + kg * 8];
      a1[mi] = *(const bf16x8*)&zb[(size_t)ra * 64 + 32 + kg * 8];
    }
  }
  f32x4 acc[2][8];
#pragma unroll
  for (int mi = 0; mi < 2; ++mi)
#pragma unroll
    for (int f = 0; f < 8; ++f) acc[mi][f] = f32x4{0.f, 0.f, 0.f, 0.f};
#pragma unroll
  for (int f = 0; f < 8; ++f) {
    bf16x8 b0 = *(const bf16x8*)&WTl[(f * 16 + m16) * 72 + kg * 8];
    bf16x8 b1 = *(const bf16x8*)&WTl[(f * 16 + m16) * 72 + 32 + kg * 8];
#pragma unroll
    for (int mi = 0; mi < 2; ++mi) {
      acc[mi][f] = __builtin_amdgcn_mfma_f32_16x16x32_bf16(a0[mi], b0, acc[mi][f], 0, 0, 0);
      acc[mi][f] = __builtin_amdgcn_mfma_f32_16x16x32_bf16(a1[mi], b1, acc[mi][f], 0, 0, 0);
    }
  }
  __syncthreads();  // WTl no longer needed; reuse as stats scratch
  float* Ss = (float*)WTl;   // [8][128]
  float* Sq = Ss + 1024;     // [8][128]
#pragma unroll
  for (int mi = 0; mi < 2; ++mi) {
    const int rwb = r0 + w * 32 + mi * 16 + kg * 4;
#pragma unroll
    for (int f = 0; f < 8; ++f) {
      int col = f * 16 + m16;
      float bc = bias[col];
      float cs = 0.f, cq = 0.f;
#pragma unroll
      for (int j = 0; j < 4; ++j) {
        int rw = rwb + j;
        if (rw < NN) {
          float v = acc[mi][f][j] + bc;
          z2b[(size_t)rw * 128 + col] = (unsigned short)f2bf(v);
          cs += v;
          cq += v * v;
        }
      }
      cs += __shfl_xor(cs, 16); cs += __shfl_xor(cs, 32);
      cq += __shfl_xor(cq, 16); cq += __shfl_xor(cq, 32);
      if (kg == 0) {
        Ss[(w * 2 + mi) * 128 + col] = cs;
        Sq[(w * 2 + mi) * 128 + col] = cq;
      }
    }
  }
  __syncthreads();
  if (t < 128) {
    float ss = 0.f, qq = 0.f;
#pragma unroll
    for (int g = 0; g < 8; ++g) {
      ss += Ss[g * 128 + t];
      qq += Sq[g * 128 + t];
    }
    partials[blockIdx.x * 256 + t] = ss;
    partials[blockIdx.x * 256 + 128 + t] = qq;
  }
  // ---- tail-block finalize ----
  __threadfence();
  __syncthreads();
  if (t == 0) lastf = (atomicAdd(ctr, 1) == NBLK_G - 1) ? 1 : 0;
  __syncthreads();
  if (!lastf) return;
  float s = 0.f;  // thread t folds stream t over all blocks
#pragma unroll 16
  for (int b = 0; b < NBLK_G; ++b) s += partials[b * 256 + t];
  float* L = (float*)WTl;
  L[t] = s;
  __syncthreads();
  if (t < 128) {
    float ss = L[t], qq = L[128 + t];
    float invN = 1.0f / NN;
    float mu = ss * invN;
    float var = qq * invN - mu * mu;
    float rs = rsqrtf(var + BN_EPS) * gamma[t];
    stout[t] = rs;
    stout[128 + t] = beta[t] - mu * rs;
  }
  if (t == 0) *ctr = 0;  // self-reset for the next fused dispatch
}

// MFMA GEMM2 with optional fused tail-block BN finalize:
// h = relu( relu(bn1(z2)) @ W2 + b2 ), bf16 in/out; STATS: emit [scale64|shift64].
template <bool STATS>
__global__ __launch_bounds__(TPB) void k_gemm2(const unsigned short* __restrict__ z2b,
                                               const unsigned short* __restrict__ w2b,
                                               const float* __restrict__ bias,
                                               const float* __restrict__ bnst,
                                               unsigned short* __restrict__ outp,
                                               float* __restrict__ partials,
                                               const float* __restrict__ gamma,
                                               const float* __restrict__ beta,
                                               float* __restrict__ stout,
                                               int* __restrict__ ctr) {
  __shared__ __align__(16) unsigned short WTl[64 * 136];  // 17.4KB; reused for stats
  __shared__ float scl[128], shl[128];
  __shared__ int lastf;
  const int t = threadIdx.x;
  const int r0 = blockIdx.x * 128;
#pragma unroll
  for (int it = 0; it < 4096 / TPB; ++it) {
    int i2 = t + it * TPB;
    unsigned v = ((const unsigned*)w2b)[i2];
    int idx = 2 * i2;
    int k = idx >> 6, n = idx & 63;  // n even
    WTl[n * 136 + k] = (unsigned short)(v & 0xFFFF);
    WTl[(n + 1) * 136 + k] = (unsigned short)(v >> 16);
  }
  if (t < 128) {
    scl[t] = bnst[t];
    shl[t] = bnst[128 + t];
  }
  __syncthreads();

  const int w = t >> 6, lane = t & 63;
  const int m16 = lane & 15, kg = lane >> 4;
  f32x4 acc[2][4];
#pragma unroll
  for (int mi = 0; mi < 2; ++mi)
#pragma unroll
    for (int f = 0; f < 4; ++f) acc[mi][f] = f32x4{0.f, 0.f, 0.f, 0.f};
#pragma unroll
  for (int s = 0; s < 4; ++s) {
    int k0 = s * 32 + kg * 8;
    bf16x8 a[2];
#pragma unroll
    for (int mi = 0; mi < 2; ++mi) {
      int ra = r0 + w * 32 + mi * 16 + m16;
      a[mi] = bf16x8{0, 0, 0, 0, 0, 0, 0, 0};
      if (ra < NN) {
        bf16x8 raw = *(const bf16x8*)&z2b[(size_t)ra * 128 + k0];
#pragma unroll
        for (int i = 0; i < 8; ++i) {
          float v = bf2f((unsigned)(unsigned short)raw[i]);
          v = fmaxf(fmaf(v, scl[k0 + i], shl[k0 + i]), 0.f);
          a[mi][i] = (short)f2bf(v);
        }
      }
    }
#pragma unroll
    for (int f = 0; f < 4; ++f) {
      bf16x8 b = *(const bf16x8*)&WTl[(f * 16 + m16) * 136 + k0];
#pragma unroll
      for (int mi = 0; mi < 2; ++mi)
        acc[mi][f] = __builtin_amdgcn_mfma_f32_16x16x32_bf16(a[mi], b, acc[mi][f], 0, 0, 0);
    }
  }
  __syncthreads();
  float* Ss = (float*)WTl;  // [8][64]
  float* Sq = Ss + 512;
#pragma unroll
  for (int mi = 0; mi < 2; ++mi) {
    const int rwb = r0 + w * 32 + mi * 16 + kg * 4;
#pragma unroll
    for (int f = 0; f < 4; ++f) {
      int col = f * 16 + m16;
      float bc = bias[col];
      float cs = 0.f, cq = 0.f;
#pragma unroll
      for (int j = 0; j < 4; ++j) {
        int rw = rwb + j;
        if (rw < NN) {
          float v = fmaxf(acc[mi][f][j] + bc, 0.f);
          outp[(size_t)rw * 64 + col] = (unsigned short)f2bf(v);
          if constexpr (STATS) {
            cs += v;
            cq += v * v;
          }
        }
      }
      if constexpr (STATS) {
        cs += __shfl_xor(cs, 16); cs += __shfl_xor(cs, 32);
        cq += __shfl_xor(cq, 16); cq += __shfl_xor(cq, 32);
        if (kg == 0) {
          Ss[(w * 2 + mi) * 64 + col] = cs;
          Sq[(w * 2 + mi) * 64 + col] = cq;
        }
      }
    }
  }
  if constexpr (STATS) {
    __syncthreads();
    if (t < 64) {
      float ss = 0.f, qq = 0.f;
#pragma unroll
      for (int g = 0; g < 8; ++g) {
        ss += Ss[g * 64 + t];
        qq += Sq[g * 64 + t];
      }
      partials[blockIdx.x * 128 + t] = ss;
      partials[blockIdx.x * 128 + 64 + t] = qq;
    }
    // ---- tail-block finalize ----
    __threadfence();
    __syncthreads();
    if (t == 0) lastf = (atomicAdd(ctr, 1) == NBLK_G - 1) ? 1 : 0;
    __syncthreads();
    if (!lastf) return;
    // 256 threads on 128 streams: thread t folds stream (t&127), half (t>>7)
    const int j = t & 127, hb = t >> 7;
    float s = 0.f;
#pragma unroll 16
    for (int bb = 0; bb < NBLK_G / 2; ++bb)
      s += partials[(hb * (NBLK_G / 2) + bb) * 128 + j];
    float* L = (float*)WTl;
    L[t] = s;
    __syncthreads();
    if (t < 64) {
      float ss = L[t] + L[128 + t];
      float qq = L[64 + t] + L[192 + t];
      float invN = 1.0f / NN;
      float mu = ss * invN;
      float var = qq * invN - mu * mu;
      float rs = rsqrtf(var + BN_EPS) * gamma[t];
      stout[t] = rs;
      stout[64 + t] = beta[t] - mu * rs;
    }
    if (t == 0) *ctr = 0;
  }
}

// Fused pool + head: block per graph.
__global__ void k_poolhead(const unsigned* __restrict__ h_bf,
                           const int* __restrict__ batch,
                           const float* __restrict__ Wh1, const float* __restrict__ bh1,
                           const float* __restrict__ Wh2, const float* __restrict__ bh2,
                           float* __restrict__ out) {
  __shared__ float lds[2 * TPB];
  __shared__ float gl[64];
  __shared__ float hidl[32];
  int gi = blockIdx.x;
  int col = threadIdx.x & 31, grp = threadIdx.x >> 5;
  int a = 0, b = NN;
  while (a < b) { int m = (a + b) >> 1; if (batch[m] < gi) a = m + 1; else b = m; }
  int lo = a;
  b = NN;
  while (a < b) { int m = (a + b) >> 1; if (batch[m] < gi + 1) a = m + 1; else b = m; }
  int hi = a;
  float a0 = 0.f, a1 = 0.f;
  for (int n = lo + grp; n < hi; n += 8) {
    unsigned u = h_bf[(size_t)n * 32 + col];
    a0 += bf2f(u & 0xFFFF);
    a1 += bf2f(u >> 16);
  }
  lds[threadIdx.x] = a0;
  lds[TPB + threadIdx.x] = a1;
  __syncthreads();
  if (grp == 0) {
#pragma unroll
    for (int k = 1; k < 8; ++k) {
      a0 += lds[k * 32 + col];
      a1 += lds[TPB + k * 32 + col];
    }
    gl[2 * col] = a0;
    gl[2 * col + 1] = a1;
  }
  __syncthreads();
  if (threadIdx.x < 32) {
    int j = threadIdx.x;
    float hid = bh1[j];
    for (int k = 0; k < 64; ++k) hid = fmaf(gl[k], Wh1[k * 32 + j], hid);
    hidl[j] = fmaxf(hid, 0.f);
  }
  __syncthreads();
  if (threadIdx.x < 10) {
    int j = threadIdx.x;
    float o = bh2[j];
#pragma unroll
    for (int k = 0; k < 32; ++k) o = fmaf(hidl[k], Wh2[k * 10 + j], o);
    out[gi * 10 + j] = o;
  }
}

extern "C" void kernel_launch(void* const* d_in, const int* in_sizes, int n_in,
                              void* d_out, int out_size, void* d_ws, size_t ws_size,
                              hipStream_t stream) {
  const int* x = (const int*)d_in[0];
  const int* ei = (const int*)d_in[1];
  const int* batch = (const int*)d_in[2];
  const float* emb = (const float*)d_in[3];
  const float* W1 = (const float*)d_in[4];
  const float* b1 = (const float*)d_in[5];
  const float* g1 = (const float*)d_in[6];
  const float* bt1 = (const float*)d_in[7];
  const float* W2 = (const float*)d_in[8];
  const float* b2 = (const float*)d_in[9];
  const float* gbn = (const float*)d_in[10];
  const float* bbn = (const float*)d_in[11];
  const float* Wh1 = (const float*)d_in[12];
  const float* bh1 = (const float*)d_in[13];
  const float* Wh2 = (const float*)d_in[14];
  const float* bh2 = (const float*)d_in[15];
  float* out = (float*)d_out;

  const int* e_src = ei;
  const int* e_dst = ei + NE;

  char* ws = (char*)d_ws;
  size_t off = 0;
  auto alloc = [&](size_t bytes) -> void* {
    void* p = ws + off;
    off = (off + bytes + 255) & ~(size_t)255;
    return p;
  };
  unsigned* h_bf = (unsigned*)alloc((size_t)NN * 64 * 2);
  unsigned* zb = (unsigned*)alloc((size_t)NN * 64 * 2);
  unsigned short* z2b = (unsigned short*)alloc((size_t)NN * 128 * 2);
  unsigned short* srcs = (unsigned short*)alloc((size_t)NE * 2);
  unsigned char* rank8 = (unsigned char*)alloc((size_t)NE);
  int* row_ptr = (int*)alloc((size_t)(NN + 1) * 4);
  int* incl = (int*)alloc((size_t)NN * 4);
  int* btot = (int*)alloc(256 * 4);
  float* partials = (float*)alloc((size_t)NBLK_G * 256 * 4);
  float* statsL = (float*)alloc(4 * 256 * 4);
  float* statsH = (float*)alloc(3 * 128 * 4);
  int* counts = (int*)alloc((size_t)NN * 4);
  unsigned* histpart = (unsigned*)alloc((size_t)HIST_BLKS * HIST_WORDS * 4);
  unsigned short* w1b = (unsigned short*)alloc(32768 * 2);
  unsigned short* w2b = (unsigned short*)alloc(32768 * 2);
  int* ctr = (int*)alloc(256);

  k_wcvt<<<256, TPB, 0, stream>>>(W1, W2, w1b, w2b, ctr);
  k_hist_lds<<<HIST_BLKS, TPB, 0, stream>>>(e_dst, histpart, rank8);
  k_hist_scan<<<(HIST_WORDS + TPB - 1) / TPB, TPB, 0, stream>>>(histpart, counts);

  int nScanBlocks = (NN + TPB - 1) / TPB;  // 196
  k_scan1<<<nScanBlocks, TPB, 0, stream>>>(counts, incl, btot);
  k_scan23<<<nScanBlocks, TPB, 0, stream>>>(incl, btot, row_ptr);
  k_fill_embed<<<EDGE_BLKS + EMB_BLKS, TPB, 0, stream>>>(e_src, e_dst, histpart, rank8,
                                                         row_ptr, srcs, x, emb, h_bf);

  int gAgg = (NN * 64 + TPB - 1) / TPB;  // 12500 (wave per node)

  for (int i = 0; i < 4; ++i) {
    const unsigned short* w1i = w1b + (size_t)i * 8192;
    const unsigned short* w2i = w2b + (size_t)i * 8192;
    const float* b1i = b1 + (size_t)i * 128;
    const float* g1i = g1 + (size_t)i * 128;
    const float* bt1i = bt1 + (size_t)i * 128;
    const float* b2i = b2 + (size_t)i * 64;
    float* stL = statsL + (size_t)i * 256;

    if (i == 0)
      k_aggregate_bf<false><<<gAgg, TPB, 0, stream>>>(h_bf, row_ptr, srcs, nullptr, zb);
    else
      k_aggregate_bf<true><<<gAgg, TPB, 0, stream>>>(h_bf, row_ptr, srcs,
                                                     statsH + (size_t)(i - 1) * 128, zb);

    k_gemm1<<<NBLK_G, TPB, 0, stream>>>((const unsigned short*)zb, w1i, b1i, z2b, partials,
                                        g1i, bt1i, stL, ctr);

    if (i < 3) {
      float* stH = statsH + (size_t)i * 128;
      k_gemm2<true><<<NBLK_G, TPB, 0, stream>>>(z2b, w2i, b2i, stL, (unsigned short*)h_bf,
                                                partials, gbn + (size_t)i * 64,
                                                bbn + (size_t)i * 64, stH, ctr);
    } else {
      k_gemm2<false><<<NBLK_G, TPB, 0, stream>>>(z2b, w2i, b2i, stL, (unsigned short*)h_bf,
                                                 partials, nullptr, nullptr, nullptr, ctr);
    }
  }

  k_poolhead<<<NG, TPB, 0, stream>>>(h_bf, batch, Wh1, bh1, Wh2, bh2, out);
}

// Round 18
// 306.891 us; speedup vs baseline: 2.0136x; 2.0136x over previous
//
#include <hip/hip_runtime.h>

#define NN 50000
#define NE 800000
#define NG 512
#define TPB 256
#define BN_EPS 1e-5f
#define NBLK_G 400       // GEMM grid: ceil(NN/128)=391, padded to 400 so finalize
                         // trip count is integral for C=128 (G=8,IT=50) and C=64 (G=16,IT=25)
#define EDGE_BLKS 3125   // NE/TPB exactly
#define EMB_BLKS 6250    // NN*32/TPB exactly
#define HIST_BLKS 256
#define HIST_EPB 3125    // NE/HIST_BLKS
#define HIST_WORDS 12500 // NN/4 packed u8x4 words
#define TPB_FIN 1024

typedef __attribute__((ext_vector_type(8))) short bf16x8;
typedef __attribute__((ext_vector_type(4))) float f32x4;

__device__ __forceinline__ float bf2f(unsigned u) {  // low 16 bits = bf16
  return __uint_as_float(u << 16);
}
__device__ __forceinline__ unsigned f2bf(float f) {
  unsigned u = __float_as_uint(f);
  u += 0x7FFFu + ((u >> 16) & 1u);  // round-to-nearest-even
  return u >> 16;
}

// Convert all layers' W1/W2 to bf16 once (GEMM blocks then stage 8KB not 16KB).
__global__ void k_wcvt(const float* __restrict__ W1, const float* __restrict__ W2,
                       unsigned short* __restrict__ w1b, unsigned short* __restrict__ w2b) {
  int i = blockIdx.x * TPB + threadIdx.x;  // 65536 threads
  if (i < 32768)
    w1b[i] = (unsigned short)f2bf(W1[i]);
  else
    w2b[i - 32768] = (unsigned short)f2bf(W2[i - 32768]);
}

// Pass 1: per-block LDS-privatized histogram + per-edge within-block rank.
__global__ __launch_bounds__(TPB) void k_hist_lds(const int* __restrict__ dst,
                                                  unsigned* __restrict__ partial,
                                                  unsigned char* __restrict__ rank8) {
  __shared__ unsigned hist[HIST_WORDS];
  const int t = threadIdx.x, b = blockIdx.x;
  for (int w = t; w < HIST_WORDS; w += TPB) hist[w] = 0u;
  __syncthreads();
  const int* dp = dst + b * HIST_EPB;
  unsigned char* rp = rank8 + b * HIST_EPB;
  for (int it = t; it < HIST_EPB; it += TPB) {
    int d = dp[it];
    unsigned sh = 8u * (d & 3);
    unsigned old = atomicAdd(&hist[d >> 2], 1u << sh);
    rp[it] = (unsigned char)((old >> sh) & 255u);
  }
  __syncthreads();
  unsigned* out = partial + (size_t)b * HIST_WORDS;
  for (int w = t; w < HIST_WORDS; w += TPB) out[w] = hist[w];
}

// Pass 2: exclusive prefix over the HIST_BLKS block histograms in place
// (packed u8 lanes, degree < 255 so no carries); emit total counts.
__global__ void k_hist_scan(unsigned* __restrict__ partial, int* __restrict__ counts) {
  int w = blockIdx.x * TPB + threadIdx.x;
  if (w >= HIST_WORDS) return;
  unsigned run = 0;
#pragma unroll 8
  for (int b = 0; b < HIST_BLKS; ++b) {
    unsigned v = partial[(size_t)b * HIST_WORDS + w];
    partial[(size_t)b * HIST_WORDS + w] = run;
    run += v;
  }
  *(int4*)&counts[4 * w] = make_int4((int)(run & 255u), (int)((run >> 8) & 255u),
                                     (int)((run >> 16) & 255u), (int)(run >> 24));
}

__global__ void k_scan1(const int* __restrict__ counts, int* __restrict__ incl,
                        int* __restrict__ btot) {
  __shared__ int lds[TPB];
  int i = blockIdx.x * TPB + threadIdx.x;
  int v = (i < NN) ? counts[i] : 0;
  lds[threadIdx.x] = v;
  __syncthreads();
  for (int off = 1; off < TPB; off <<= 1) {
    int t = (threadIdx.x >= off) ? lds[threadIdx.x - off] : 0;
    __syncthreads();
    lds[threadIdx.x] += t;
    __syncthreads();
  }
  if (i < NN) incl[i] = lds[threadIdx.x];
  if (threadIdx.x == TPB - 1) btot[blockIdx.x] = lds[TPB - 1];
}

__global__ void k_scan23(const int* __restrict__ incl, const int* __restrict__ btot,
                         int* __restrict__ row_ptr) {
  __shared__ int lds[TPB];
  const int t = threadIdx.x, b = blockIdx.x;
  lds[t] = (t < 196 && t < b) ? btot[t] : 0;
  __syncthreads();
  for (int off = TPB / 2; off > 0; off >>= 1) {
    if (t < off) lds[t] += lds[t + off];
    __syncthreads();
  }
  int S = lds[0];
  int i = b * TPB + t;
  if (i == 0) row_ptr[0] = 0;
  if (i < NN) row_ptr[i + 1] = incl[i] + S;
}

// LDS-free atomic-free fill + embed at full occupancy (r14 structure).
__global__ __launch_bounds__(TPB) void k_fill_embed(
    const int* __restrict__ src, const int* __restrict__ dst,
    const unsigned* __restrict__ partial, const unsigned char* __restrict__ rank8,
    const int* __restrict__ row_ptr, unsigned short* __restrict__ srcs,
    const int* __restrict__ x, const float* __restrict__ emb,
    unsigned* __restrict__ h_bf) {
  int b = blockIdx.x;
  if (b < EDGE_BLKS) {
    int e = b * TPB + threadIdx.x;
    int d = dst[e];
    int bh = e / HIST_EPB;
    unsigned base = (partial[(size_t)bh * HIST_WORDS + (d >> 2)] >> (8u * (d & 3))) & 255u;
    int pos = row_ptr[d] + (int)base + (int)rank8[e];
    srcs[pos] = (unsigned short)src[e];
  } else {
    int i = (b - EDGE_BLKS) * TPB + threadIdx.x;  // < NN*32 exactly
    int n = i >> 5, l = i & 31;
    float2 ev = *(const float2*)&emb[x[n] * 64 + 2 * l];
    h_bf[i] = f2bf(ev.x) | (f2bf(ev.y) << 16);
  }
}

// Aggregate over bf16 h, optional BN affine folded in -> packed bf16.
// Clamped batch-16 (r15): always 8 gathers in flight per half-wave.
template <bool BN>
__global__ void k_aggregate_bf(const unsigned* __restrict__ h_bf,
                               const int* __restrict__ row_ptr,
                               const unsigned short* __restrict__ srcs,
                               const float* __restrict__ bnst,
                               unsigned* __restrict__ zb) {
  int wid = (blockIdx.x * TPB + threadIdx.x) >> 6;
  int lane = threadIdx.x & 63;
  if (wid >= NN) return;
  int half = lane >> 5, l = lane & 31;
  int beg = row_ptr[wid], end = row_ptr[wid + 1];
  float a0 = 0.f, a1 = 0.f;
  if (half == 0) {
    unsigned u = h_bf[(size_t)wid * 32 + l];
    a0 = bf2f(u & 0xFFFF);
    a1 = bf2f(u >> 16);
  }
  for (int e = beg + half; e < end; e += 16) {
    int idx[8];
#pragma unroll
    for (int k = 0; k < 8; ++k) {
      int ee = e + 2 * k;
      idx[k] = srcs[ee < end ? ee : end - 1];
    }
    unsigned uu[8];
#pragma unroll
    for (int k = 0; k < 8; ++k) uu[k] = h_bf[(size_t)idx[k] * 32 + l];
#pragma unroll
    for (int k = 0; k < 8; ++k) {
      bool v = (e + 2 * k) < end;
      a0 += v ? bf2f(uu[k] & 0xFFFF) : 0.f;
      a1 += v ? bf2f(uu[k] >> 16) : 0.f;
    }
  }
  a0 += __shfl_xor(a0, 32);
  a1 += __shfl_xor(a1, 32);
  if (half == 0) {
    float zv0, zv1;
    if constexpr (BN) {
      float2 scv = *(const float2*)&bnst[2 * l];
      float2 shv = *(const float2*)&bnst[64 + 2 * l];
      float d1 = (float)(1 + end - beg);
      zv0 = fmaf(scv.x, a0, d1 * shv.x);
      zv1 = fmaf(scv.y, a1, d1 * shv.y);
    } else {
      zv0 = a0;
      zv1 = a1;
    }
    zb[(size_t)wid * 32 + l] = f2bf(zv0) | (f2bf(zv1) << 16);
  }
}

// MFMA GEMM1: z2[N,128] = z[N,64] @ W[64,128] + b1 (bf16 in/out, f32 acc).
// 128 rows/block (wave w owns rows 32w..32w+32, 2 m-frags), W pre-converted
// bf16 staged once per block. C/D layout: col=lane&15, row=(lane>>4)*4+reg.
__global__ __launch_bounds__(TPB) void k_gemm1(const unsigned short* __restrict__ zb,
                                               const unsigned short* __restrict__ w1b,
                                               const float* __restrict__ bias,
                                               unsigned short* __restrict__ z2b,
                                               float* __restrict__ partials) {
  __shared__ __align__(16) unsigned short WTl[128 * 72];  // 18KB; reused for stats
  const int t = threadIdx.x;
  const int r0 = blockIdx.x * 128;
  // stage bf16 W [64][128] -> WTl[n*72+k] (uint reads: pair (k,n),(k,n+1))
#pragma unroll
  for (int it = 0; it < 4096 / TPB; ++it) {
    int i2 = t + it * TPB;
    unsigned v = ((const unsigned*)w1b)[i2];
    int idx = 2 * i2;
    int k = idx >> 7, n = idx & 127;  // n even
    WTl[n * 72 + k] = (unsigned short)(v & 0xFFFF);
    WTl[(n + 1) * 72 + k] = (unsigned short)(v >> 16);
  }
  __syncthreads();

  const int w = t >> 6, lane = t & 63;
  const int m16 = lane & 15, kg = lane >> 4;
  bf16x8 a0[2], a1[2];
#pragma unroll
  for (int mi = 0; mi < 2; ++mi) {
    int ra = r0 + w * 32 + mi * 16 + m16;
    a0[mi] = bf16x8{0, 0, 0, 0, 0, 0, 0, 0};
    a1[mi] = bf16x8{0, 0, 0, 0, 0, 0, 0, 0};
    if (ra < NN) {
      a0[mi] = *(const bf16x8*)&zb[(size_t)ra * 64 + kg * 8];
      a1[mi] = *(const bf16x8*)&zb[(size_t)ra * 64 + 32 + kg * 8];
    }
  }
  f32x4 acc[2][8];
#pragma unroll
  for (int mi = 0; mi < 2; ++mi)
#pragma unroll
    for (int f = 0; f < 8; ++f) acc[mi][f] = f32x4{0.f, 0.f, 0.f, 0.f};
#pragma unroll
  for (int f = 0; f < 8; ++f) {
    bf16x8 b0 = *(const bf16x8*)&WTl[(f * 16 + m16) * 72 + kg * 8];
    bf16x8 b1 = *(const bf16x8*)&WTl[(f * 16 + m16) * 72 + 32 + kg * 8];
#pragma unroll
    for (int mi = 0; mi < 2; ++mi) {
      acc[mi][f] = __builtin_amdgcn_mfma_f32_16x16x32_bf16(a0[mi], b0, acc[mi][f], 0, 0, 0);
      acc[mi][f] = __builtin_amdgcn_mfma_f32_16x16x32_bf16(a1[mi], b1, acc[mi][f], 0, 0, 0);
    }
  }
  __syncthreads();  // WTl no longer needed; reuse as stats scratch
  float* Ss = (float*)WTl;   // [8][128]
  float* Sq = Ss + 1024;     // [8][128]
#pragma unroll
  for (int mi = 0; mi < 2; ++mi) {
    const int rwb = r0 + w * 32 + mi * 16 + kg * 4;
#pragma unroll
    for (int f = 0; f < 8; ++f) {
      int col = f * 16 + m16;
      float bc = bias[col];
      float cs = 0.f, cq = 0.f;
#pragma unroll
      for (int j = 0; j < 4; ++j) {
        int rw = rwb + j;
        if (rw < NN) {
          float v = acc[mi][f][j] + bc;
          z2b[(size_t)rw * 128 + col] = (unsigned short)f2bf(v);
          cs += v;
          cq += v * v;
        }
      }
      cs += __shfl_xor(cs, 16); cs += __shfl_xor(cs, 32);
      cq += __shfl_xor(cq, 16); cq += __shfl_xor(cq, 32);
      if (kg == 0) {
        Ss[(w * 2 + mi) * 128 + col] = cs;
        Sq[(w * 2 + mi) * 128 + col] = cq;
      }
    }
  }
  __syncthreads();
  if (t < 128) {
    float ss = 0.f, qq = 0.f;
#pragma unroll
    for (int g = 0; g < 8; ++g) {
      ss += Ss[g * 128 + t];
      qq += Sq[g * 128 + t];
    }
    partials[blockIdx.x * 256 + t] = ss;
    partials[blockIdx.x * 256 + 128 + t] = qq;
  }
}

// MFMA GEMM2: h[N,64] = relu( relu(bn1(z2)) @ W[128,64] + b2 ), bf16 in/out.
// 128 rows/block; BN affine + relu applied in-register on A fragments.
template <bool STATS>
__global__ __launch_bounds__(TPB) void k_gemm2(const unsigned short* __restrict__ z2b,
                                               const unsigned short* __restrict__ w2b,
                                               const float* __restrict__ bias,
                                               const float* __restrict__ bnst,
                                               unsigned short* __restrict__ outp,
                                               float* __restrict__ partials) {
  __shared__ __align__(16) unsigned short WTl[64 * 136];  // 17.4KB; reused for stats
  __shared__ float scl[128], shl[128];
  const int t = threadIdx.x;
  const int r0 = blockIdx.x * 128;
#pragma unroll
  for (int it = 0; it < 4096 / TPB; ++it) {
    int i2 = t + it * TPB;
    unsigned v = ((const unsigned*)w2b)[i2];
    int idx = 2 * i2;
    int k = idx >> 6, n = idx & 63;  // n even
    WTl[n * 136 + k] = (unsigned short)(v & 0xFFFF);
    WTl[(n + 1) * 136 + k] = (unsigned short)(v >> 16);
  }
  if (t < 128) {
    scl[t] = bnst[t];
    shl[t] = bnst[128 + t];
  }
  __syncthreads();

  const int w = t >> 6, lane = t & 63;
  const int m16 = lane & 15, kg = lane >> 4;
  f32x4 acc[2][4];
#pragma unroll
  for (int mi = 0; mi < 2; ++mi)
#pragma unroll
    for (int f = 0; f < 4; ++f) acc[mi][f] = f32x4{0.f, 0.f, 0.f, 0.f};
#pragma unroll
  for (int s = 0; s < 4; ++s) {
    int k0 = s * 32 + kg * 8;
    bf16x8 a[2];
#pragma unroll
    for (int mi = 0; mi < 2; ++mi) {
      int ra = r0 + w * 32 + mi * 16 + m16;
      a[mi] = bf16x8{0, 0, 0, 0, 0, 0, 0, 0};
      if (ra < NN) {
        bf16x8 raw = *(const bf16x8*)&z2b[(size_t)ra * 128 + k0];
#pragma unroll
        for (int i = 0; i < 8; ++i) {
          float v = bf2f((unsigned)(unsigned short)raw[i]);
          v = fmaxf(fmaf(v, scl[k0 + i], shl[k0 + i]), 0.f);
          a[mi][i] = (short)f2bf(v);
        }
      }
    }
#pragma unroll
    for (int f = 0; f < 4; ++f) {
      bf16x8 b = *(const bf16x8*)&WTl[(f * 16 + m16) * 136 + k0];
#pragma unroll
      for (int mi = 0; mi < 2; ++mi)
        acc[mi][f] = __builtin_amdgcn_mfma_f32_16x16x32_bf16(a[mi], b, acc[mi][f], 0, 0, 0);
    }
  }
  __syncthreads();
  float* Ss = (float*)WTl;  // [8][64]
  float* Sq = Ss + 512;
#pragma unroll
  for (int mi = 0; mi < 2; ++mi) {
    const int rwb = r0 + w * 32 + mi * 16 + kg * 4;
#pragma unroll
    for (int f = 0; f < 4; ++f) {
      int col = f * 16 + m16;
      float bc = bias[col];
      float cs = 0.f, cq = 0.f;
#pragma unroll
      for (int j = 0; j < 4; ++j) {
        int rw = rwb + j;
        if (rw < NN) {
          float v = fmaxf(acc[mi][f][j] + bc, 0.f);
          outp[(size_t)rw * 64 + col] = (unsigned short)f2bf(v);
          if constexpr (STATS) {
            cs += v;
            cq += v * v;
          }
        }
      }
      if constexpr (STATS) {
        cs += __shfl_xor(cs, 16); cs += __shfl_xor(cs, 32);
        cq += __shfl_xor(cq, 16); cq += __shfl_xor(cq, 32);
        if (kg == 0) {
          Ss[(w * 2 + mi) * 64 + col] = cs;
          Sq[(w * 2 + mi) * 64 + col] = cq;
        }
      }
    }
  }
  if constexpr (STATS) {
    __syncthreads();
    if (t < 64) {
      float ss = 0.f, qq = 0.f;
#pragma unroll
      for (int g = 0; g < 8; ++g) {
        ss += Ss[g * 64 + t];
        qq += Sq[g * 64 + t];
      }
      partials[blockIdx.x * 128 + t] = ss;
      partials[blockIdx.x * 128 + 64 + t] = qq;
    }
  }
}

// Fold partials: constant trip count + unroll-8, LDS tree-fold, 1024 thr.
template <int C>
__global__ __launch_bounds__(TPB_FIN) void k_finalize(const float* __restrict__ partials,
                                                      const float* __restrict__ gamma,
                                                      const float* __restrict__ beta,
                                                      float* __restrict__ out) {
  constexpr int G = TPB_FIN / C;
  constexpr int IT = NBLK_G / G;
  __shared__ float lds[2 * TPB_FIN];
  const int c = threadIdx.x % C, g = threadIdx.x / C;
  const float* p = partials + g * 2 * C + c;
  float s = 0.f, s2 = 0.f;
#pragma unroll 8
  for (int bb = 0; bb < IT; ++bb) {
    s += p[(size_t)bb * G * 2 * C];
    s2 += p[(size_t)bb * G * 2 * C + C];
  }
  lds[threadIdx.x] = s;
  lds[TPB_FIN + threadIdx.x] = s2;
  __syncthreads();
  if (g == 0) {
#pragma unroll
    for (int k = 1; k < G; ++k) {
      s += lds[k * C + c];
      s2 += lds[TPB_FIN + k * C + c];
    }
    float invN = 1.0f / NN;
    float mu = s * invN;
    float var = s2 * invN - mu * mu;
    float rs = rsqrtf(var + BN_EPS) * gamma[c];
    out[c] = rs;
    out[C + c] = beta[c] - mu * rs;
  }
}

// Fused pool + head: block per graph.
__global__ void k_poolhead(const unsigned* __restrict__ h_bf,
                           const int* __restrict__ batch,
                           const float* __restrict__ Wh1, const float* __restrict__ bh1,
                           const float* __restrict__ Wh2, const float* __restrict__ bh2,
                           float* __restrict__ out) {
  __shared__ float lds[2 * TPB];
  __shared__ float gl[64];
  __shared__ float hidl[32];
  int gi = blockIdx.x;
  int col = threadIdx.x & 31, grp = threadIdx.x >> 5;
  int a = 0, b = NN;
  while (a < b) { int m = (a + b) >> 1; if (batch[m] < gi) a = m + 1; else b = m; }
  int lo = a;
  b = NN;
  while (a < b) { int m = (a + b) >> 1; if (batch[m] < gi + 1) a = m + 1; else b = m; }
  int hi = a;
  float a0 = 0.f, a1 = 0.f;
  for (int n = lo + grp; n < hi; n += 8) {
    unsigned u = h_bf[(size_t)n * 32 + col];
    a0 += bf2f(u & 0xFFFF);
    a1 += bf2f(u >> 16);
  }
  lds[threadIdx.x] = a0;
  lds[TPB + threadIdx.x] = a1;
  __syncthreads();
  if (grp == 0) {
#pragma unroll
    for (int k = 1; k < 8; ++k) {
      a0 += lds[k * 32 + col];
      a1 += lds[TPB + k * 32 + col];
    }
    gl[2 * col] = a0;
    gl[2 * col + 1] = a1;
  }
  __syncthreads();
  if (threadIdx.x < 32) {
    int j = threadIdx.x;
    float hid = bh1[j];
    for (int k = 0; k < 64; ++k) hid = fmaf(gl[k], Wh1[k * 32 + j], hid);
    hidl[j] = fmaxf(hid, 0.f);
  }
  __syncthreads();
  if (threadIdx.x < 10) {
    int j = threadIdx.x;
    float o = bh2[j];
#pragma unroll
    for (int k = 0; k < 32; ++k) o = fmaf(hidl[k], Wh2[k * 10 + j], o);
    out[gi * 10 + j] = o;
  }
}

extern "C" void kernel_launch(void* const* d_in, const int* in_sizes, int n_in,
                              void* d_out, int out_size, void* d_ws, size_t ws_size,
                              hipStream_t stream) {
  const int* x = (const int*)d_in[0];
  const int* ei = (const int*)d_in[1];
  const int* batch = (const int*)d_in[2];
  const float* emb = (const float*)d_in[3];
  const float* W1 = (const float*)d_in[4];
  const float* b1 = (const float*)d_in[5];
  const float* g1 = (const float*)d_in[6];
  const float* bt1 = (const float*)d_in[7];
  const float* W2 = (const float*)d_in[8];
  const float* b2 = (const float*)d_in[9];
  const float* gbn = (const float*)d_in[10];
  const float* bbn = (const float*)d_in[11];
  const float* Wh1 = (const float*)d_in[12];
  const float* bh1 = (const float*)d_in[13];
  const float* Wh2 = (const float*)d_in[14];
  const float* bh2 = (const float*)d_in[15];
  float* out = (float*)d_out;

  const int* e_src = ei;
  const int* e_dst = ei + NE;

  char* ws = (char*)d_ws;
  size_t off = 0;
  auto alloc = [&](size_t bytes) -> void* {
    void* p = ws + off;
    off = (off + bytes + 255) & ~(size_t)255;
    return p;
  };
  unsigned* h_bf = (unsigned*)alloc((size_t)NN * 64 * 2);
  unsigned* zb = (unsigned*)alloc((size_t)NN * 64 * 2);
  unsigned short* z2b = (unsigned short*)alloc((size_t)NN * 128 * 2);
  unsigned short* srcs = (unsigned short*)alloc((size_t)NE * 2);
  unsigned char* rank8 = (unsigned char*)alloc((size_t)NE);
  int* row_ptr = (int*)alloc((size_t)(NN + 1) * 4);
  int* incl = (int*)alloc((size_t)NN * 4);
  int* btot = (int*)alloc(256 * 4);
  float* partials = (float*)alloc((size_t)NBLK_G * 256 * 4);
  float* statsL = (float*)alloc(4 * 256 * 4);
  float* statsH = (float*)alloc(3 * 128 * 4);
  int* counts = (int*)alloc((size_t)NN * 4);
  unsigned* histpart = (unsigned*)alloc((size_t)HIST_BLKS * HIST_WORDS * 4);
  unsigned short* w1b = (unsigned short*)alloc(32768 * 2);
  unsigned short* w2b = (unsigned short*)alloc(32768 * 2);

  k_wcvt<<<256, TPB, 0, stream>>>(W1, W2, w1b, w2b);
  k_hist_lds<<<HIST_BLKS, TPB, 0, stream>>>(e_dst, histpart, rank8);
  k_hist_scan<<<(HIST_WORDS + TPB - 1) / TPB, TPB, 0, stream>>>(histpart, counts);

  int nScanBlocks = (NN + TPB - 1) / TPB;  // 196
  k_scan1<<<nScanBlocks, TPB, 0, stream>>>(counts, incl, btot);
  k_scan23<<<nScanBlocks, TPB, 0, stream>>>(incl, btot, row_ptr);
  k_fill_embed<<<EDGE_BLKS + EMB_BLKS, TPB, 0, stream>>>(e_src, e_dst, histpart, rank8,
                                                         row_ptr, srcs, x, emb, h_bf);

  int gAgg = (NN * 64 + TPB - 1) / TPB;  // 12500 (wave per node)

  for (int i = 0; i < 4; ++i) {
    const unsigned short* w1i = w1b + (size_t)i * 8192;
    const unsigned short* w2i = w2b + (size_t)i * 8192;
    const float* b1i = b1 + (size_t)i * 128;
    const float* g1i = g1 + (size_t)i * 128;
    const float* bt1i = bt1 + (size_t)i * 128;
    const float* b2i = b2 + (size_t)i * 64;
    float* stL = statsL + (size_t)i * 256;

    if (i == 0)
      k_aggregate_bf<false><<<gAgg, TPB, 0, stream>>>(h_bf, row_ptr, srcs, nullptr, zb);
    else
      k_aggregate_bf<true><<<gAgg, TPB, 0, stream>>>(h_bf, row_ptr, srcs,
                                                     statsH + (size_t)(i - 1) * 128, zb);

    k_gemm1<<<NBLK_G, TPB, 0, stream>>>((const unsigned short*)zb, w1i, b1i, z2b, partials);
    k_finalize<128><<<1, TPB_FIN, 0, stream>>>(partials, g1i, bt1i, stL);

    if (i < 3) {
      float* stH = statsH + (size_t)i * 128;
      k_gemm2<true><<<NBLK_G, TPB, 0, stream>>>(z2b, w2i, b2i, stL,
                                                (unsigned short*)h_bf, partials);
      k_finalize<64><<<1, TPB_FIN, 0, stream>>>(partials, gbn + (size_t)i * 64,
                                                bbn + (size_t)i * 64, stH);
    } else {
      k_gemm2<false><<<NBLK_G, TPB, 0, stream>>>(z2b, w2i, b2i, stL,
                                                 (unsigned short*)h_bf, partials);
    }
  }

  k_poolhead<<<NG, TPB, 0, stream>>>(h_bf, batch, Wh1, bh1, Wh2, bh2, out);
}